// Round 8
// baseline (11463.706 us; speedup 1.0000x reference)
//
#include <hip/hip_runtime.h>
#include <stdint.h>

#define SEQ   1024
#define BATCH 32
#define HID   512
#define G3    1536
#define NW    32          // rec workgroups per direction
#define THREADS 384       // 6 waves
#define FSTR  256         // flag spacing in ints (1KB)
#define CSTR  64          // prodcnt spacing in ints (256B)
#define CH    16          // steps per Xi chunk
#define NCH   64          // chunks per layer
#define NG    192         // gate-row groups of 16, ng = dir*96 + g*32 + wg
#define NPROD 192         // producer WGs
#define GS    17          // padded stride for gbuf/hold (bank-conflict-free publish)

typedef __attribute__((ext_vector_type(8))) short  short8;
typedef __attribute__((ext_vector_type(4))) float  f32x4;
typedef __attribute__((ext_vector_type(4))) unsigned short us4;
typedef unsigned long long ull;

__device__ __forceinline__ unsigned short f2bf(float f) {
  union { float f; unsigned int u; } v; v.f = f;
  unsigned int u = v.u;
  return (unsigned short)((u + 0x7FFFu + ((u >> 16) & 1u)) >> 16);
}
__device__ __forceinline__ float bf2f(unsigned short u) {
  union { unsigned int i; float f; } v; v.i = ((unsigned int)u) << 16; return v.f;
}
__device__ __forceinline__ short8 pack8(const float* __restrict__ p) {
  short8 o;
#pragma unroll
  for (int i = 0; i < 8; i++) o[i] = (short)f2bf(p[i]);
  return o;
}

// fp32 W [3072][K] -> bf16 B-fragment chunks [ng][kc][64 lane] x 16B
__global__ void cvt_wb(const float* __restrict__ w, short8* __restrict__ out, int kcx, int nc) {
  int c = blockIdx.x * blockDim.x + threadIdx.x;
  if (c >= nc) return;
  int lane = c & 63, r = c >> 6;     // r = ng*kcx + kc
  int kc = r % kcx, ng = r / kcx;
  int n   = ng * 16 + (lane & 15);
  int col = kc * 32 + (lane >> 4) * 8;
  int K = kcx * 32;
  out[c] = pack8(w + (size_t)n * K + col);
}

// One dispatch per layer, grid=256: blocks 0..63 = recurrence; 64..255 = producers
// (4 ng-tiles each, weights LDS-cached, 4 timestep-phases). All exchange via sc1
// (agent scope, L3-served). h readiness = step-parity tag in LSB of short#7 of each
// 16B chunk (single-lane dwordx4 store = atomic 16B unit) — consumer poll-load IS
// the data load; no drains or flag RTs on the critical path.
template<int KCX, bool WRITE_Y>
__global__ __launch_bounds__(THREADS, 1) void gru_mega(
    const void* __restrict__ Ain,      // KCX==8: fp32 x [T][32][256]; else short8 [T][2][KCX][64]
    short8* __restrict__ yout,         // [T][2][32][64] chunks (or null)
    const short8* __restrict__ wb,     // [NG][KCX][64] B-fragments
    const float* __restrict__ whh,     // [2][G3][HID]
    const float* __restrict__ bih,     // [3072]
    const float* __restrict__ bhh,     // [3072]
    us4* __restrict__ Xic,             // [2 slot][CH][NG][2 mi][64]
    short8* __restrict__ hbuf,         // this layer: [2 dir][2 par][2 mi][16 kc][64]
    int* __restrict__ flags,           // [2][NW][FSTR] (producer pacing only)
    int* __restrict__ prodcnt,         // [NCH][CSTR]
    float* __restrict__ hout)          // [2][BATCH][HID] slice of d_out
{
  extern __shared__ short8 wlds[];     // producers: [4][KCX][64]
  __shared__ float gbuf[4 * 32 * GS];  // [4 gate-row][32 b][GS] preactivations
  __shared__ float hold[32 * GS];      // [32 b][GS] fp32 state

  const int tid  = threadIdx.x;
  const int lane = tid & 63;
  const int wave = tid >> 6;
  const int quad = lane >> 4;
  const int l15  = lane & 15;

  if (blockIdx.x >= 64) {
    // ================= producer =================
    const int p    = blockIdx.x - 64;  // 0..191
    const int ngq  = p >> 2;           // 0..47 -> 4 ng each
    const int tg   = p & 3;            // timestep phase
    const int dirp = (ngq >= 24) ? 1 : 0;
    const int ng0  = ngq * 4;
    int* fl = flags + dirp * NW * FSTR;

    for (int idx = tid; idx < 4 * KCX * 64; idx += THREADS)
      wlds[idx] = wb[(size_t)ng0 * KCX * 64 + idx];
    __syncthreads();

    for (int c = 0; c < NCH; c++) {
      const int tgt = (c >= 2) ? CH * (c - 1) : 0;
      if (wave == 0) {
        while (true) {
          int v = (lane < NW)
                    ? __hip_atomic_load(&fl[lane * FSTR], __ATOMIC_RELAXED, __HIP_MEMORY_SCOPE_AGENT)
                    : tgt;
          if (__all(v >= tgt)) break;
          __builtin_amdgcn_s_sleep(4);
        }
      }
      __syncthreads();
      for (int i = 0; i < 4; i++) {
        const int sl = i * 4 + tg;
        const int s  = c * CH + sl;
        const int t  = dirp ? (SEQ - 1 - s) : s;
        for (int task = wave; task < 8; task += 6) {
          const int mi = task & 1;
          const int ng = task >> 1;    // 0..3
          short8 a[KCX];
          if constexpr (KCX == 8) {
            const float* xr = (const float*)Ain + ((size_t)t * 32 + mi * 16 + l15) * 256 + quad * 8;
#pragma unroll
            for (int kc = 0; kc < KCX; kc++) a[kc] = pack8(xr + kc * 32);
          } else {
            const short8* ap = (const short8*)Ain + ((size_t)(t * 2 + mi) * KCX) * 64 + lane;
#pragma unroll
            for (int kc = 0; kc < KCX; kc++) a[kc] = ap[kc * 64];
          }
          const short8* bp = wlds + ng * (KCX * 64) + lane;
          f32x4 ac0 = (f32x4){0.f, 0.f, 0.f, 0.f};
          f32x4 ac1 = (f32x4){0.f, 0.f, 0.f, 0.f};
#pragma unroll
          for (int kc = 0; kc < KCX; kc += 2) {
            ac0 = __builtin_amdgcn_mfma_f32_16x16x32_bf16(a[kc],     bp[kc * 64],       ac0, 0, 0, 0);
            ac1 = __builtin_amdgcn_mfma_f32_16x16x32_bf16(a[kc + 1], bp[(kc + 1) * 64], ac1, 0, 0, 0);
          }
          const int ngg = ng0 + ng;
          const int n   = ngg * 16 + l15;
          const int gg  = (ngg % 96) >> 5;
          const float bias = bih[n] + (gg < 2 ? bhh[n] : 0.f);
          us4 o;
#pragma unroll
          for (int r = 0; r < 4; r++) o[r] = f2bf(ac0[r] + ac1[r] + bias);
          us4* dst = Xic + (((size_t)(c & 1) * CH + sl) * NG + ngg) * 128 + mi * 64 + lane;
          asm volatile("global_store_dwordx2 %0, %1, off sc1" :: "v"(dst), "v"(o) : "memory");
        }
      }
      asm volatile("s_waitcnt vmcnt(0)" ::: "memory");  // Xi visible before counter
      __syncthreads();
      if (tid == 0)
        __hip_atomic_fetch_add(&prodcnt[c * CSTR], 1, __ATOMIC_RELAXED, __HIP_MEMORY_SCOPE_AGENT);
    }
    return;
  }

  // ================= recurrence =================
  const int mi  = wave & 1;
  const int g   = wave >> 1;
  const int dir = blockIdx.x >> 5;
  const int wg  = blockIdx.x & 31;
  const int j0  = wg * 16;
  const bool rev = (dir == 1);
  const int ngR = dir * 96 + g * 32 + wg;

  short8 wh[16];
  {
    const float* pw = whh + (size_t)dir * G3 * HID + (size_t)(g * HID + j0 + l15) * HID + quad * 8;
#pragma unroll
    for (int kc = 0; kc < 16; kc++) wh[kc] = pack8(pw + kc * 32);
  }
  const float bh = bhh[dir * G3 + g * HID + j0 + l15];

  for (int idx = tid; idx < 32 * GS; idx += THREADS) hold[idx] = 0.f;
  __syncthreads();

  int* fl = flags + dir * NW * FSTR;
  char* hb = (char*)(hbuf + (size_t)dir * 2 * 2048);   // [2 par][32KB]

  for (int s = 0; s < SEQ; s++) {
    const int t  = rev ? (SEQ - 1 - s) : s;
    const int c  = s >> 4;
    const int sl = s & 15;

    if (sl == 0) {   // chunk gate: Xi chunk c fully produced
      while (__hip_atomic_load(&prodcnt[c * CSTR], __ATOMIC_RELAXED, __HIP_MEMORY_SCOPE_AGENT) < NPROD)
        __builtin_amdgcn_s_sleep(1);
    }

    const char* xp = (const char*)Xic
        + ((((size_t)(c & 1) * CH + sl) * NG + ngR) * 128 + mi * 64 + lane) * 8;
    ull xi64;
    f32x4 p0 = (f32x4){0.f, 0.f, 0.f, 0.f};
    f32x4 p1 = (f32x4){0.f, 0.f, 0.f, 0.f};

    if (s > 0) {
      const char* hp = hb + (size_t)((s - 1) & 1) * 32768 + (size_t)mi * 16384 + (size_t)lane * 16;
      const int tag = ((s - 1) >> 1) & 1;
      short8 a0, a1, a2, a3, a4, a5, a6, a7, a8, a9, a10, a11, a12, a13, a14, a15;
      while (true) {   // poll-load: data + readiness in one RT
        asm volatile(
            "global_load_dwordx2 %16, %21, off sc1\n\t"
            "global_load_dwordx4 %0, %17, off sc1\n\t"
            "global_load_dwordx4 %1, %17, off offset:1024 sc1\n\t"
            "global_load_dwordx4 %2, %17, off offset:2048 sc1\n\t"
            "global_load_dwordx4 %3, %17, off offset:3072 sc1\n\t"
            "global_load_dwordx4 %4, %18, off sc1\n\t"
            "global_load_dwordx4 %5, %18, off offset:1024 sc1\n\t"
            "global_load_dwordx4 %6, %18, off offset:2048 sc1\n\t"
            "global_load_dwordx4 %7, %18, off offset:3072 sc1\n\t"
            "global_load_dwordx4 %8, %19, off sc1\n\t"
            "global_load_dwordx4 %9, %19, off offset:1024 sc1\n\t"
            "global_load_dwordx4 %10, %19, off offset:2048 sc1\n\t"
            "global_load_dwordx4 %11, %19, off offset:3072 sc1\n\t"
            "global_load_dwordx4 %12, %20, off sc1\n\t"
            "global_load_dwordx4 %13, %20, off offset:1024 sc1\n\t"
            "global_load_dwordx4 %14, %20, off offset:2048 sc1\n\t"
            "global_load_dwordx4 %15, %20, off offset:3072 sc1\n\t"
            "s_waitcnt vmcnt(0)"
            : "=&v"(a0), "=&v"(a1), "=&v"(a2), "=&v"(a3),
              "=&v"(a4), "=&v"(a5), "=&v"(a6), "=&v"(a7),
              "=&v"(a8), "=&v"(a9), "=&v"(a10), "=&v"(a11),
              "=&v"(a12), "=&v"(a13), "=&v"(a14), "=&v"(a15), "=&v"(xi64)
            : "v"(hp), "v"(hp + 4096), "v"(hp + 8192), "v"(hp + 12288), "v"(xp)
            : "memory");
        bool ok = ((a0[7]  & 1) == tag) & ((a1[7]  & 1) == tag)
                & ((a2[7]  & 1) == tag) & ((a3[7]  & 1) == tag)
                & ((a4[7]  & 1) == tag) & ((a5[7]  & 1) == tag)
                & ((a6[7]  & 1) == tag) & ((a7[7]  & 1) == tag)
                & ((a8[7]  & 1) == tag) & ((a9[7]  & 1) == tag)
                & ((a10[7] & 1) == tag) & ((a11[7] & 1) == tag)
                & ((a12[7] & 1) == tag) & ((a13[7] & 1) == tag)
                & ((a14[7] & 1) == tag) & ((a15[7] & 1) == tag);
        if (__all(ok)) break;
      }
      p0 = __builtin_amdgcn_mfma_f32_16x16x32_bf16(a0,  wh[0],  p0, 0, 0, 0);
      p1 = __builtin_amdgcn_mfma_f32_16x16x32_bf16(a1,  wh[1],  p1, 0, 0, 0);
      p0 = __builtin_amdgcn_mfma_f32_16x16x32_bf16(a2,  wh[2],  p0, 0, 0, 0);
      p1 = __builtin_amdgcn_mfma_f32_16x16x32_bf16(a3,  wh[3],  p1, 0, 0, 0);
      p0 = __builtin_amdgcn_mfma_f32_16x16x32_bf16(a4,  wh[4],  p0, 0, 0, 0);
      p1 = __builtin_amdgcn_mfma_f32_16x16x32_bf16(a5,  wh[5],  p1, 0, 0, 0);
      p0 = __builtin_amdgcn_mfma_f32_16x16x32_bf16(a6,  wh[6],  p0, 0, 0, 0);
      p1 = __builtin_amdgcn_mfma_f32_16x16x32_bf16(a7,  wh[7],  p1, 0, 0, 0);
      p0 = __builtin_amdgcn_mfma_f32_16x16x32_bf16(a8,  wh[8],  p0, 0, 0, 0);
      p1 = __builtin_amdgcn_mfma_f32_16x16x32_bf16(a9,  wh[9],  p1, 0, 0, 0);
      p0 = __builtin_amdgcn_mfma_f32_16x16x32_bf16(a10, wh[10], p0, 0, 0, 0);
      p1 = __builtin_amdgcn_mfma_f32_16x16x32_bf16(a11, wh[11], p1, 0, 0, 0);
      p0 = __builtin_amdgcn_mfma_f32_16x16x32_bf16(a12, wh[12], p0, 0, 0, 0);
      p1 = __builtin_amdgcn_mfma_f32_16x16x32_bf16(a13, wh[13], p1, 0, 0, 0);
      p0 = __builtin_amdgcn_mfma_f32_16x16x32_bf16(a14, wh[14], p0, 0, 0, 0);
      p1 = __builtin_amdgcn_mfma_f32_16x16x32_bf16(a15, wh[15], p1, 0, 0, 0);
    } else {
      asm volatile("global_load_dwordx2 %0, %1, off sc1\n\ts_waitcnt vmcnt(0)"
                   : "=&v"(xi64) : "v"(xp) : "memory");
    }

    // ---- merge Xi + h-projection into padded gbuf ----
#pragma unroll
    for (int r = 0; r < 4; r++) {
      int m = mi * 16 + quad * 4 + r;
      float xv = bf2f((unsigned short)(xi64 >> (16 * r)));
      if (g < 2) {
        gbuf[(g * 32 + m) * GS + l15] = xv + p0[r] + p1[r];
      } else {
        gbuf[(2 * 32 + m) * GS + l15] = xv;
        gbuf[(3 * 32 + m) * GS + l15] = bh + p0[r] + p1[r];
      }
    }
    __syncthreads();   // all waves' Xi consumed + gbuf complete

    // ---- wave0: gates + state + tagged single-chunk publish (64 chunks) ----
    if (tid < 64) {
      const int b     = tid >> 1;
      const int khalf = tid & 1;
      short8 val;
      float hv[8];
#pragma unroll
      for (int jj = 0; jj < 8; jj++) {
        int j = khalf * 8 + jj;
        float pr = gbuf[(0 * 32 + b) * GS + j];
        float pz = gbuf[(1 * 32 + b) * GS + j];
        float px = gbuf[(2 * 32 + b) * GS + j];
        float ph = gbuf[(3 * 32 + b) * GS + j];
        float rr = 1.f / (1.f + __expf(-pr));
        float zz = 1.f / (1.f + __expf(-pz));
        float a2 = px + rr * ph;
        float ex = __expf(2.f * a2);
        float nn = 1.f - 2.f / (ex + 1.f);        // tanh(a2)
        float hp2 = hold[b * GS + j];
        float hnew = (1.f - zz) * nn + zz * hp2;
        hold[b * GS + j] = hnew;
        hv[jj] = hnew;
        val[jj] = (short)f2bf(hnew);
      }
      val[7] = (short)((val[7] & ~1) | ((s >> 1) & 1));   // step-parity tag
      const int k8  = wg * 2 + khalf;
      const int kc  = k8 >> 2;
      const int qd  = k8 & 3;
      const int mib = b >> 4;
      const int lnb = b & 15;
      char* dst = hb + (size_t)(s & 1) * 32768 + (size_t)mib * 16384
                + (size_t)kc * 1024 + (size_t)(qd * 16 + lnb) * 16;
      asm volatile("global_store_dwordx4 %0, %1, off sc1" :: "v"(dst), "v"(val) : "memory");
      if (WRITE_Y)
        yout[((size_t)(t * 2 + mib) * 32 + (dir << 4) + kc) * 64 + qd * 16 + lnb] = val;
      if (s == SEQ - 1) {
#pragma unroll
        for (int jj = 0; jj < 8; jj++)
          hout[((size_t)dir * 32 + b) * HID + j0 + khalf * 8 + jj] = hv[jj];
      }
      if (tid == 0)
        __hip_atomic_store(&fl[wg * FSTR], s + 1, __ATOMIC_RELAXED, __HIP_MEMORY_SCOPE_AGENT);
    }
    // no trailing barrier: next step's gbuf writes are gated by the tag-poll,
    // which requires this WG's publish to have committed.
  }
}

extern "C" void kernel_launch(void* const* d_in, const int* in_sizes, int n_in,
                              void* d_out, int out_size, void* d_ws, size_t ws_size,
                              hipStream_t stream)
{
  const float* x       = (const float*)d_in[0];
  const float* w_ih_l0 = (const float*)d_in[1];
  const float* w_hh_l0 = (const float*)d_in[2];
  const float* b_ih_l0 = (const float*)d_in[3];
  const float* b_hh_l0 = (const float*)d_in[4];
  const float* w_ih_lr = (const float*)d_in[5];
  const float* w_hh_lr = (const float*)d_in[6];
  const float* b_ih_lr = (const float*)d_in[7];
  const float* b_hh_lr = (const float*)d_in[8];
  float* out = (float*)d_out;

  char* ws = (char*)d_ws;
  size_t off = 0;
  auto alloc = [&](size_t bytes) {
    char* p = ws + off;
    off += (bytes + 255) & ~(size_t)255;
    return p;
  };
  short8* y0   = (short8*)alloc((size_t)SEQ * 2 * 32 * 64 * 16);   // 64 MB
  short8* y1   = (short8*)alloc((size_t)SEQ * 2 * 32 * 64 * 16);   // 64 MB
  short8* wb   = (short8*)alloc((size_t)NG * 32 * 64 * 16);        // 6 MB
  short8* hbuf = (short8*)alloc((size_t)3 * 2 * 2 * 2048 * 16);    // 3 x 128 KB (per layer)
  int*    flags   = (int*)alloc((size_t)3 * 2 * NW * FSTR * 4);    // 192 KB
  int*    prodcnt = (int*)alloc((size_t)3 * NCH * CSTR * 4);       // 48 KB
  us4*    Xic  = (us4*)alloc((size_t)2 * CH * NG * 2 * 64 * 8);    // 6 MB

  hipMemsetAsync(flags, 0, (size_t)3 * 2 * NW * FSTR * 4, stream);
  hipMemsetAsync(prodcnt, 0, (size_t)3 * NCH * CSTR * 4, stream);
  hipMemsetAsync(hbuf, 0xFF, (size_t)3 * 2 * 2 * 2048 * 16, stream);  // tag=1: no false match

  const int smem0 = 4 * 8  * 64 * 16;   //  32 KB producer weights
  const int smem1 = 4 * 32 * 64 * 16;   // 128 KB
  hipFuncSetAttribute(reinterpret_cast<const void*>(gru_mega<8, true>),
                      hipFuncAttributeMaxDynamicSharedMemorySize, smem0);
  hipFuncSetAttribute(reinterpret_cast<const void*>(gru_mega<32, true>),
                      hipFuncAttributeMaxDynamicSharedMemorySize, smem1);
  hipFuncSetAttribute(reinterpret_cast<const void*>(gru_mega<32, false>),
                      hipFuncAttributeMaxDynamicSharedMemorySize, smem1);

  // ---- layer 0 ----
  {
    int nc = NG * 8 * 64;
    cvt_wb<<<(nc + 255) / 256, 256, 0, stream>>>(w_ih_l0, wb, 8, nc);
    gru_mega<8, true><<<256, THREADS, smem0, stream>>>(
        x, y0, wb, w_hh_l0, b_ih_l0, b_hh_l0, Xic, hbuf, flags, prodcnt, out);
  }
  // ---- layer 1 ----
  {
    int nc = NG * 32 * 64;
    cvt_wb<<<(nc + 255) / 256, 256, 0, stream>>>(w_ih_lr, wb, 32, nc);
    gru_mega<32, true><<<256, THREADS, smem1, stream>>>(
        y0, y1, wb, w_hh_lr, b_ih_lr, b_hh_lr, Xic, hbuf + 8192,
        flags + 2 * NW * FSTR, prodcnt + NCH * CSTR, out + 2 * BATCH * HID);
  }
  // ---- layer 2 ----
  {
    int nc = NG * 32 * 64;
    cvt_wb<<<(nc + 255) / 256, 256, 0, stream>>>(w_ih_lr + (size_t)2 * G3 * 1024, wb, 32, nc);
    gru_mega<32, false><<<256, THREADS, smem1, stream>>>(
        y1, nullptr, wb, w_hh_lr + (size_t)2 * G3 * HID,
        b_ih_lr + 2 * G3, b_hh_lr + 2 * G3, Xic, hbuf + 16384,
        flags + 4 * NW * FSTR, prodcnt + 2 * NCH * CSTR, out + 4 * BATCH * HID);
  }
}